// Round 3
// baseline (2718.574 us; speedup 1.0000x reference)
//
#include <hip/hip_runtime.h>
#include <math.h>

// Problem constants: B=256, T=512, D=128, H=128 (3H=384), U=64, A=10, LAMDA=0.5
#define B_ 256
#define T_ 512
#define D_ 128
#define H_ 128
#define BH_ 32768      // B_*H_
#define NG 1308160     // 511*256*10 gumbels per agent

// ---------------- threefry2x32 (exact JAX semantics) ----------------
__device__ __forceinline__ void tf2x32(unsigned k0, unsigned k1, unsigned x0, unsigned x1,
                                       unsigned& o0, unsigned& o1) {
  unsigned k2 = k0 ^ k1 ^ 0x1BD11BDAu;
  unsigned v0 = x0 + k0, v1 = x1 + k1;
#define TFR(r) { v0 += v1; v1 = (v1 << (r)) | (v1 >> (32 - (r))); v1 ^= v0; }
  TFR(13) TFR(15) TFR(26) TFR(6)   v0 += k1; v1 += k2 + 1u;
  TFR(17) TFR(29) TFR(16) TFR(24)  v0 += k2; v1 += k0 + 2u;
  TFR(13) TFR(15) TFR(26) TFR(6)   v0 += k0; v1 += k1 + 3u;
  TFR(17) TFR(29) TFR(16) TFR(24)  v0 += k1; v1 += k2 + 4u;
  TFR(13) TFR(15) TFR(26) TFR(6)   v0 += k2; v1 += k0 + 5u;
#undef TFR
  o0 = v0; o1 = v1;
}

__device__ __forceinline__ float gumbel_f(unsigned bits) {
  const float tiny = 1.17549435e-38f;
  float u = __uint_as_float((bits >> 9) | 0x3f800000u) - 1.0f;
  u = u + tiny;
  u = fmaxf(tiny, u);
  return -logf(-logf(u));
}

// ---------------- P0: split keys (jax_threefry_partitionable=True) ----------------
__global__ void p0_keys(unsigned* __restrict__ keys_tab) {
  int i = blockIdx.x * blockDim.x + threadIdx.x;
  if (i >= 1024) return;
  unsigned o0, o1;
  tf2x32(0u, 42u, 0u, (unsigned)i, o0, o1);
  keys_tab[2 * i] = o0; keys_tab[2 * i + 1] = o1;
}

// ---------------- P3: gumbel table for agent 1 only (agent 2 inlined in p2) ----------------
__global__ void p3_gumbel(const unsigned* __restrict__ keys_tab, float* __restrict__ g1) {
  int rem = blockIdx.x * blockDim.x + threadIdx.x;
  if (rem >= NG) return;
  int tm1 = rem / 2560;
  int f = rem - tm1 * 2560;
  int t = tm1 + 1;
  unsigned k0 = keys_tab[2 * (2 * t)], k1 = keys_tab[2 * (2 * t) + 1];
  unsigned b1, b2;
  tf2x32(k0, k1, 0u, (unsigned)f, b1, b2);
  g1[rem] = gumbel_f(b1 ^ b2);
}

// ---------------- P2: agent-2 actions (depend only on x), gumbel inlined ----------------
__global__ __launch_bounds__(256) void p2_a2(const float* __restrict__ x,
    const float* __restrict__ w1, const float* __restrict__ b1,
    const float* __restrict__ w2, const float* __restrict__ b2,
    const unsigned* __restrict__ keys_tab, int* __restrict__ a2_tab) {
  __shared__ float4 w1v[32][64];
  __shared__ __align__(16) float w2s[10][64];
  __shared__ float b1s[64];
  __shared__ float b2s[10];
  __shared__ __align__(16) float zs[4][8][64];
  int tid = threadIdx.x, wv = tid >> 6, lane = tid & 63;
  for (int idx = tid; idx < 2048; idx += 256) {
    int c = idx >> 6, m = idx & 63;
    w1v[c][m] = ((const float4*)(w1 + m * 128))[c];
  }
  for (int idx = tid; idx < 640; idx += 256) w2s[idx >> 6][idx & 63] = w2[idx];
  if (tid < 64) b1s[tid] = b1[tid];
  if (tid < 10) b2s[tid] = b2[tid];
  __syncthreads();
  int s0 = blockIdx.x * 32 + wv * 8;
  int t = (s0 >> 8) + 1;
  unsigned k0 = keys_tab[2 * (2 * t + 1)], k1 = keys_tab[2 * (2 * t + 1) + 1];
  int m = lane;
  for (int pr = 0; pr < 4; pr++) {
    int sA = s0 + 2 * pr, sB = sA + 1;
    int bA = sA & 255, bB = sB & 255;
    const float4* xA = (const float4*)(x + ((size_t)bA * T_ + t) * D_);
    const float4* xB = (const float4*)(x + ((size_t)bB * T_ + t) * D_);
    float accA = 0.f, accB = 0.f;
    #pragma unroll
    for (int c = 0; c < 32; c++) {
      float4 w4 = w1v[c][m];
      float4 xa = xA[c], xb = xB[c];
      accA += w4.x * xa.x + w4.y * xa.y + w4.z * xa.z + w4.w * xa.w;
      accB += w4.x * xb.x + w4.y * xb.y + w4.z * xb.z + w4.w * xb.w;
    }
    zs[wv][2 * pr][m]     = tanhf(accA + b1s[m]);
    zs[wv][2 * pr + 1][m] = tanhf(accB + b1s[m]);
  }
  __syncthreads();
  int a = lane & 15, kc = lane >> 4;
  for (int i = 0; i < 8; i++) {
    int s = s0 + i, b = s & 255;
    float p = 0.f;
    if (a < 10) {
      const float4* zp = (const float4*)(&zs[wv][i][16 * kc]);
      const float4* wp = (const float4*)(&w2s[a][16 * kc]);
      #pragma unroll
      for (int c = 0; c < 4; c++) {
        float4 zv = zp[c], w4 = wp[c];
        p += w4.x * zv.x + w4.y * zv.y + w4.z * zv.z + w4.w * zv.w;
      }
    }
    p += __shfl_xor(p, 16);
    p += __shfl_xor(p, 32);
    float val = -3.0e38f;
    if (a < 10) {
      unsigned bb1, bb2;
      tf2x32(k0, k1, 0u, (unsigned)(b * 10 + a), bb1, bb2);
      val = (p + b2s[a]) + gumbel_f(bb1 ^ bb2);
    }
    float best = 0.f; int bi = 0;
    #pragma unroll
    for (int aa = 0; aa < 10; aa++) {
      float v = __shfl(val, aa);
      if (aa == 0 || v > best) { best = v; bi = aa; }
    }
    if (lane == 0) a2_tab[(size_t)(t - 1) * 256 + b] = bi;
  }
}

// ---------------- G: gi[bt][r] = x[bt]·w_ih[r] + b_ih[r]  (parallel GEMM) ----------------
__global__ __launch_bounds__(384, 2) void gemm_gi(const float* __restrict__ x,
    const float* __restrict__ w_ih, const float* __restrict__ b_ih,
    float* __restrict__ gi) {
  __shared__ __align__(16) float xt[16 * 128];
  int tid = threadIdx.x;
  size_t bt0 = (size_t)blockIdx.x * 16;
  const float4* xg = (const float4*)(x + bt0 * 128);
  float4* xts = (float4*)xt;
  xts[tid] = xg[tid];
  if (tid < 128) xts[384 + tid] = xg[384 + tid];
  // weight row in registers (128 VGPR)
  float4 wrw[32];
  const float4* wg = (const float4*)(w_ih + (size_t)tid * 128);
  #pragma unroll
  for (int c = 0; c < 32; c++) wrw[c] = wg[c];
  float br = b_ih[tid];
  __syncthreads();
  #pragma unroll 1
  for (int i = 0; i < 16; i++) {
    const float4* xr = (const float4*)(xt + i * 128);
    float ax = 0.f, ay = 0.f, az = 0.f, aw = 0.f;
    #pragma unroll
    for (int c = 0; c < 32; c++) {
      float4 xv = xr[c];
      ax += wrw[c].x * xv.x; ay += wrw[c].y * xv.y;
      az += wrw[c].z * xv.z; aw += wrw[c].w * xv.w;
    }
    gi[(bt0 + i) * 384 + tid] = ((ax + ay) + (az + aw)) + br;
  }
}

// ---------------- S: sequential per-batch kernel (1 block = 1 batch elem) ----------------
// Structure per step: [waves0-5: y=W_hh·h -> ycache | wave6: gi stage + h store + z1 lo
//                      | wave7: rng stage + z1 hi] -> barrier -> argmax(all) + gates(128) -> barrier
__global__ __launch_bounds__(512, 2) void seq_kernel(
    const float* __restrict__ gi_glob, const int* __restrict__ mask,
    const float* __restrict__ w_hh, const float* __restrict__ b_hh,
    const float* __restrict__ a1w1, const float* __restrict__ a1b1,
    const float* __restrict__ a1w2, const float* __restrict__ a1b2,
    const float* __restrict__ g1_tab, const int* __restrict__ a2_tab,
    float* __restrict__ out) {
  __shared__ __align__(16) float ring[10][128];   // ring[s] = h_s (s = t%10)
  __shared__ __align__(16) float yc[10][384];     // yc[s] = W_hh · ring[s]
  __shared__ __align__(16) float hbuf[128];       // h_{t-1}
  __shared__ __align__(16) float ghi[384];        // staged gi[b][t]
  __shared__ __align__(16) float obs6[128], obs7[128];
  __shared__ __align__(16) float z1buf[64];
  __shared__ __align__(16) float lastbuf[128];
  __shared__ __align__(16) float w1s[64 * 132];   // a1w1 rows padded to 132 floats
  __shared__ __align__(16) float w2buf[10][64];
  __shared__ float bhhs[384], b1s[64], b2s[10];
  __shared__ float g1buf[10];
  __shared__ float plogbuf[2][16];
  __shared__ int a2s_lds;
  __shared__ int redi[8];
  __shared__ int last_s;

  const int tid = threadIdx.x;
  const int wave = tid >> 6, lane = tid & 63;
  const int b = blockIdx.x;

  // ---- register-resident W_hh for waves 0-5: quad-interleaved k-split ----
  // thread (q=tid>>2, qk=tid&3) owns rows {q+96i}, k-elems {16c+4qk..+3}
  float4 wr[4][8];
  const int q = tid >> 2, qk = tid & 3;
  if (tid < 384) {
    #pragma unroll
    for (int i = 0; i < 4; i++) {
      const float* basep = w_hh + (size_t)(q + 96 * i) * 128 + 4 * qk;
      #pragma unroll
      for (int c = 0; c < 8; c++) wr[i][c] = *(const float4*)(basep + 16 * c);
    }
  }

  // ---- LDS init ----
  for (int idx = tid; idx < 1280; idx += 512) ((float*)ring)[idx] = 0.f;
  for (int idx = tid; idx < 3840; idx += 512) ((float*)yc)[idx] = 0.f;
  for (int idx = tid; idx < 8192; idx += 512) w1s[(idx >> 7) * 132 + (idx & 127)] = a1w1[idx];
  for (int idx = tid; idx < 640; idx += 512) w2buf[idx >> 6][idx & 63] = a1w2[idx];
  for (int idx = tid; idx < 384; idx += 512) bhhs[idx] = b_hh[idx];
  if (tid < 64) b1s[tid] = a1b1[tid];
  if (tid < 10) b2s[tid] = a1b2[tid];
  // mask -> last index
  int mv = mask[(size_t)b * T_ + tid];
  #pragma unroll
  for (int off = 1; off < 64; off <<= 1) mv += __shfl_xor(mv, off);
  if (lane == 0) redi[wave] = mv;
  // initial prefetches (global, no LDS dep)
  const float4* gi4 = (const float4*)gi_glob;
  float4 gir0 = make_float4(0.f,0.f,0.f,0.f), gir1 = make_float4(0.f,0.f,0.f,0.f);
  if (wave == 6) {
    size_t base1 = ((size_t)b * 512 + 1) * 96;
    gir0 = gi4[base1 + lane];
    if (lane < 32) gir1 = gi4[base1 + 64 + lane];
  }
  float g1r = 0.f; int a2r = 0;
  if (wave == 7 && lane < 10) g1r = g1_tab[(size_t)b * 10 + lane];
  if (wave == 7 && lane == 12) a2r = a2_tab[b];
  __syncthreads();
  if (tid == 0) {
    int s = 0;
    #pragma unroll
    for (int w = 0; w < 8; w++) s += redi[w];
    last_s = s - 1;
  }
  __syncthreads();
  const int last = last_s;

  // ---- t = 0: h0 = gru(x0, 0) ----
  if (tid < 128) {
    int j = tid;
    const float* g0 = gi_glob + (size_t)b * 512 * 384;
    float ir = g0[j] + bhhs[j];
    float iz = g0[128 + j] + bhhs[128 + j];
    float in_ = g0[256 + j];
    float hn = bhhs[256 + j];
    float r  = 1.0f / (1.0f + expf(-ir));
    float zz = 1.0f / (1.0f + expf(-iz));
    float n  = tanhf(in_ + r * hn);
    float hnew = (1.0f - zz) * n;   // + zz*0
    hbuf[j] = hnew; ring[0][j] = hnew;
    if (0 == last) lastbuf[j] = hnew;
  }
  __syncthreads();

  // ---- t = 1..511 ----
  #pragma unroll 1
  for (int t = 1; t < T_; t++) {
    const int sn = (t + 9) % 10;   // slot of h_{t-1}
    if (tid < 384) {
      // y = W_hh · h_{t-1}  -> yc[sn]
      const float4* hb4 = (const float4*)hbuf;
      float4 a0 = make_float4(0.f,0.f,0.f,0.f), a1v = a0, a2v = a0, a3v = a0;
      #pragma unroll
      for (int c = 0; c < 8; c++) {
        float4 h4 = hb4[4 * c + qk];
        a0.x += wr[0][c].x * h4.x; a0.y += wr[0][c].y * h4.y; a0.z += wr[0][c].z * h4.z; a0.w += wr[0][c].w * h4.w;
        a1v.x += wr[1][c].x * h4.x; a1v.y += wr[1][c].y * h4.y; a1v.z += wr[1][c].z * h4.z; a1v.w += wr[1][c].w * h4.w;
        a2v.x += wr[2][c].x * h4.x; a2v.y += wr[2][c].y * h4.y; a2v.z += wr[2][c].z * h4.z; a2v.w += wr[2][c].w * h4.w;
        a3v.x += wr[3][c].x * h4.x; a3v.y += wr[3][c].y * h4.y; a3v.z += wr[3][c].z * h4.z; a3v.w += wr[3][c].w * h4.w;
      }
      float s0 = (a0.x + a0.y) + (a0.z + a0.w);
      float s1v = (a1v.x + a1v.y) + (a1v.z + a1v.w);
      float s2v = (a2v.x + a2v.y) + (a2v.z + a2v.w);
      float s3v = (a3v.x + a3v.y) + (a3v.z + a3v.w);
      s0 += __shfl_xor(s0, 1); s0 += __shfl_xor(s0, 2);
      s1v += __shfl_xor(s1v, 1); s1v += __shfl_xor(s1v, 2);
      s2v += __shfl_xor(s2v, 1); s2v += __shfl_xor(s2v, 2);
      s3v += __shfl_xor(s3v, 1); s3v += __shfl_xor(s3v, 2);
      float my = (qk == 0) ? s0 : (qk == 1) ? s1v : (qk == 2) ? s2v : s3v;
      yc[sn][q + 96 * qk] = my;
    } else if (wave == 6) {
      // stage gi for this step; store h_{t-1} to out; prefetch gi for t+1
      ((float4*)ghi)[lane] = gir0;
      if (lane < 32) ((float4*)ghi)[64 + lane] = gir1;
      if (lane < 32)
        *(float4*)(out + BH_ + ((size_t)b * 512 + (t - 1)) * 128 + 4 * lane) =
            *(const float4*)(hbuf + 4 * lane);
      if (t < 511) {
        size_t basep = ((size_t)b * 512 + t + 1) * 96;
        gir0 = gi4[basep + lane];
        if (lane < 32) gir1 = gi4[basep + 64 + lane];
      }
      // obs (own copy) + z1 rows 0..31 + partial logits
      float o0 = 0.f, o1 = 0.f;
      #pragma unroll
      for (int a = 0; a < 10; a++) {
        o0 += ring[(t + a) % 10][lane];
        o1 += ring[(t + a) % 10][64 + lane];
      }
      obs6[lane] = o0 / 10.0f; obs6[64 + lane] = o1 / 10.0f;
      {
        int m = lane >> 1, kc = lane & 1;
        const float* wrow = &w1s[m * 132];
        float ax = 0.f, ay = 0.f, az = 0.f, aw = 0.f;
        #pragma unroll
        for (int c = 0; c < 16; c++) {
          float4 w4 = *(const float4*)(wrow + 4 * (16 * kc + c));
          float4 o4 = ((const float4*)obs6)[16 * kc + c];
          ax += w4.x * o4.x; ay += w4.y * o4.y; az += w4.z * o4.z; aw += w4.w * o4.w;
        }
        float d = (ax + ay) + (az + aw);
        d += __shfl_xor(d, 1);
        if (kc == 0) z1buf[m] = tanhf(d + b1s[m]);
      }
      if (lane < 40) {
        int a = lane >> 2, k2 = lane & 3;
        int m0 = 8 * k2;
        float4 z4a = ((const float4*)(z1buf + m0))[0], z4b = ((const float4*)(z1buf + m0))[1];
        float4 wa = ((const float4*)(&w2buf[a][m0]))[0], wb = ((const float4*)(&w2buf[a][m0]))[1];
        float p = z4a.x*wa.x + z4a.y*wa.y + z4a.z*wa.z + z4a.w*wa.w
                + z4b.x*wb.x + z4b.y*wb.y + z4b.z*wb.z + z4b.w*wb.w;
        p += __shfl_xor(p, 1); p += __shfl_xor(p, 2);
        if (k2 == 0) plogbuf[0][a] = p;
      }
    } else { // wave 7
      if (lane < 10) g1buf[lane] = g1r;
      if (lane == 12) a2s_lds = a2r;
      if (t < 511) {
        if (lane < 10) g1r = g1_tab[((size_t)t * 256 + b) * 10 + lane];
        if (lane == 12) a2r = a2_tab[(size_t)t * 256 + b];
      }
      float o0 = 0.f, o1 = 0.f;
      #pragma unroll
      for (int a = 0; a < 10; a++) {
        o0 += ring[(t + a) % 10][lane];
        o1 += ring[(t + a) % 10][64 + lane];
      }
      obs7[lane] = o0 / 10.0f; obs7[64 + lane] = o1 / 10.0f;
      {
        int m = 32 + (lane >> 1), kc = lane & 1;
        const float* wrow = &w1s[m * 132];
        float ax = 0.f, ay = 0.f, az = 0.f, aw = 0.f;
        #pragma unroll
        for (int c = 0; c < 16; c++) {
          float4 w4 = *(const float4*)(wrow + 4 * (16 * kc + c));
          float4 o4 = ((const float4*)obs7)[16 * kc + c];
          ax += w4.x * o4.x; ay += w4.y * o4.y; az += w4.z * o4.z; aw += w4.w * o4.w;
        }
        float d = (ax + ay) + (az + aw);
        d += __shfl_xor(d, 1);
        if (kc == 0) z1buf[m] = tanhf(d + b1s[m]);
      }
      if (lane < 40) {
        int a = lane >> 2, k2 = lane & 3;
        int m0 = 32 + 8 * k2;
        float4 z4a = ((const float4*)(z1buf + m0))[0], z4b = ((const float4*)(z1buf + m0))[1];
        float4 wa = ((const float4*)(&w2buf[a][m0]))[0], wb = ((const float4*)(&w2buf[a][m0]))[1];
        float p = z4a.x*wa.x + z4a.y*wa.y + z4a.z*wa.z + z4a.w*wa.w
                + z4b.x*wb.x + z4b.y*wb.y + z4b.z*wb.z + z4b.w*wb.w;
        p += __shfl_xor(p, 1); p += __shfl_xor(p, 2);
        if (k2 == 0) plogbuf[1][a] = p;
      }
    }
    __syncthreads();   // B: ycache/ghi/plog/g1buf/a2s ready

    // redundant broadcast argmax (all threads; avoids another barrier)
    float best = 0.f; int bi = 0;
    #pragma unroll
    for (int a = 0; a < 10; a++) {
      float v = (plogbuf[0][a] + plogbuf[1][a] + b2s[a]) + g1buf[a];
      if (a == 0 || v > best) { best = v; bi = a; }
    }
    const int s1 = (t + bi) % 10;
    const int s2 = (t + a2s_lds) % 10;

    if (tid < 128) {
      int j = tid;
      float gh1 = bhhs[j]       + 0.5f * (0.5f * (yc[s1][j]       + yc[s2][j]))       + 0.5f * yc[sn][j];
      float gh2 = bhhs[128 + j] + 0.5f * (0.5f * (yc[s1][128 + j] + yc[s2][128 + j])) + 0.5f * yc[sn][128 + j];
      float gh3 = bhhs[256 + j] + 0.5f * (0.5f * (yc[s1][256 + j] + yc[s2][256 + j])) + 0.5f * yc[sn][256 + j];
      float gi1 = ghi[j], gi2 = ghi[128 + j], gi3 = ghi[256 + j];
      float r  = 1.0f / (1.0f + expf(-(gi1 + gh1)));
      float zz = 1.0f / (1.0f + expf(-(gi2 + gh2)));
      float n  = tanhf(gi3 + r * gh3);
      float hw = 0.5f * ((ring[s1][j] + ring[s2][j]) * 0.5f) + 0.5f * hbuf[j];
      float hnew = (1.0f - zz) * n + zz * hw;
      hbuf[j] = hnew;
      ring[t % 10][j] = hnew;
      if (t == last) lastbuf[j] = hnew;
    }
    __syncthreads();   // A for next step
  }
  if (tid < 128) {
    out[(size_t)b * H_ + tid] = lastbuf[tid];
    out[BH_ + ((size_t)b * 512 + 511) * 128 + tid] = hbuf[tid];  // h_511 (not stored in-loop)
  }
}

extern "C" void kernel_launch(void* const* d_in, const int* in_sizes, int n_in,
                              void* d_out, int out_size, void* d_ws, size_t ws_size,
                              hipStream_t stream) {
  (void)in_sizes; (void)n_in; (void)out_size; (void)ws_size;
  const float* x     = (const float*)d_in[0];
  const int*   mask  = (const int*)d_in[1];
  const float* w_ih  = (const float*)d_in[2];
  const float* w_hh  = (const float*)d_in[3];
  const float* b_ih  = (const float*)d_in[4];
  const float* b_hh  = (const float*)d_in[5];
  const float* a1w1  = (const float*)d_in[6];
  const float* a1b1  = (const float*)d_in[7];
  const float* a1w2  = (const float*)d_in[8];
  const float* a1b2  = (const float*)d_in[9];
  const float* a2w1  = (const float*)d_in[10];
  const float* a2b1  = (const float*)d_in[11];
  const float* a2w2  = (const float*)d_in[12];
  const float* a2b2  = (const float*)d_in[13];
  float* out = (float*)d_out;

  // workspace: gi table (201.3 MB) | g1 (5.2 MB) | keys | a2 actions
  float*    gi       = (float*)d_ws;                       // 131072*384 floats
  float*    g1       = gi + (size_t)131072 * 384;
  unsigned* keys_tab = (unsigned*)(g1 + NG);
  int*      a2_tab   = (int*)(keys_tab + 2048);

  p0_keys<<<4, 256, 0, stream>>>(keys_tab);
  p3_gumbel<<<5110, 256, 0, stream>>>(keys_tab, g1);
  p2_a2<<<4088, 256, 0, stream>>>(x, a2w1, a2b1, a2w2, a2b2, keys_tab, a2_tab);
  gemm_gi<<<8192, 384, 0, stream>>>(x, w_ih, b_ih, gi);
  seq_kernel<<<256, 512, 0, stream>>>(gi, mask, w_hh, b_hh,
                                      a1w1, a1b1, a1w2, a1b2, g1, a2_tab, out);
}

// Round 4
// 2181.718 us; speedup vs baseline: 1.2461x; 1.2461x over previous
//
#include <hip/hip_runtime.h>
#include <math.h>

// Problem constants: B=256, T=512, D=128, H=128 (3H=384), U=64, A=10, LAMDA=0.5
#define B_ 256
#define T_ 512
#define D_ 128
#define H_ 128
#define BH_ 32768      // B_*H_
#define NG 1308160     // 511*256*10 gumbels per agent

// LDS-ordering-only barrier: skips the vmcnt(0) drain __syncthreads() forces.
__device__ __forceinline__ void bar_lds() {
  asm volatile("s_waitcnt lgkmcnt(0)\n\ts_barrier" ::: "memory");
}

// ---------------- threefry2x32 (exact JAX semantics) ----------------
__device__ __forceinline__ void tf2x32(unsigned k0, unsigned k1, unsigned x0, unsigned x1,
                                       unsigned& o0, unsigned& o1) {
  unsigned k2 = k0 ^ k1 ^ 0x1BD11BDAu;
  unsigned v0 = x0 + k0, v1 = x1 + k1;
#define TFR(r) { v0 += v1; v1 = (v1 << (r)) | (v1 >> (32 - (r))); v1 ^= v0; }
  TFR(13) TFR(15) TFR(26) TFR(6)   v0 += k1; v1 += k2 + 1u;
  TFR(17) TFR(29) TFR(16) TFR(24)  v0 += k2; v1 += k0 + 2u;
  TFR(13) TFR(15) TFR(26) TFR(6)   v0 += k0; v1 += k1 + 3u;
  TFR(17) TFR(29) TFR(16) TFR(24)  v0 += k1; v1 += k2 + 4u;
  TFR(13) TFR(15) TFR(26) TFR(6)   v0 += k2; v1 += k0 + 5u;
#undef TFR
  o0 = v0; o1 = v1;
}

__device__ __forceinline__ float gumbel_f(unsigned bits) {
  const float tiny = 1.17549435e-38f;
  float u = __uint_as_float((bits >> 9) | 0x3f800000u) - 1.0f;
  u = u + tiny;
  u = fmaxf(tiny, u);
  return -logf(-logf(u));
}

// ---------------- P0: split keys (jax_threefry_partitionable=True) ----------------
__global__ void p0_keys(unsigned* __restrict__ keys_tab) {
  int i = blockIdx.x * blockDim.x + threadIdx.x;
  if (i >= 1024) return;
  unsigned o0, o1;
  tf2x32(0u, 42u, 0u, (unsigned)i, o0, o1);
  keys_tab[2 * i] = o0; keys_tab[2 * i + 1] = o1;
}

// ---------------- P3: gumbel table for agent 1 (agent 2 inlined in p2) ----------------
__global__ void p3_gumbel(const unsigned* __restrict__ keys_tab, float* __restrict__ g1) {
  int rem = blockIdx.x * blockDim.x + threadIdx.x;
  if (rem >= NG) return;
  int tm1 = rem / 2560;
  int f = rem - tm1 * 2560;
  int t = tm1 + 1;
  unsigned k0 = keys_tab[2 * (2 * t)], k1 = keys_tab[2 * (2 * t) + 1];
  unsigned b1, b2;
  tf2x32(k0, k1, 0u, (unsigned)f, b1, b2);
  g1[rem] = gumbel_f(b1 ^ b2);
}

// ---------------- P2: agent-2 actions (depend only on x), gumbel inlined ----------------
__global__ __launch_bounds__(256) void p2_a2(const float* __restrict__ x,
    const float* __restrict__ w1, const float* __restrict__ b1,
    const float* __restrict__ w2, const float* __restrict__ b2,
    const unsigned* __restrict__ keys_tab, int* __restrict__ a2_tab) {
  __shared__ float4 w1v[32][64];
  __shared__ __align__(16) float w2s[10][64];
  __shared__ float b1s[64];
  __shared__ float b2s[10];
  __shared__ __align__(16) float zs[4][8][64];
  int tid = threadIdx.x, wv = tid >> 6, lane = tid & 63;
  for (int idx = tid; idx < 2048; idx += 256) {
    int c = idx >> 6, m = idx & 63;
    w1v[c][m] = ((const float4*)(w1 + m * 128))[c];
  }
  for (int idx = tid; idx < 640; idx += 256) w2s[idx >> 6][idx & 63] = w2[idx];
  if (tid < 64) b1s[tid] = b1[tid];
  if (tid < 10) b2s[tid] = b2[tid];
  __syncthreads();
  int s0 = blockIdx.x * 32 + wv * 8;
  int t = (s0 >> 8) + 1;
  unsigned k0 = keys_tab[2 * (2 * t + 1)], k1 = keys_tab[2 * (2 * t + 1) + 1];
  int m = lane;
  for (int pr = 0; pr < 4; pr++) {
    int sA = s0 + 2 * pr, sB = sA + 1;
    int bA = sA & 255, bB = sB & 255;
    const float4* xA = (const float4*)(x + ((size_t)bA * T_ + t) * D_);
    const float4* xB = (const float4*)(x + ((size_t)bB * T_ + t) * D_);
    float accA = 0.f, accB = 0.f;
    #pragma unroll
    for (int c = 0; c < 32; c++) {
      float4 w4 = w1v[c][m];
      float4 xa = xA[c], xb = xB[c];
      accA += w4.x * xa.x + w4.y * xa.y + w4.z * xa.z + w4.w * xa.w;
      accB += w4.x * xb.x + w4.y * xb.y + w4.z * xb.z + w4.w * xb.w;
    }
    zs[wv][2 * pr][m]     = tanhf(accA + b1s[m]);
    zs[wv][2 * pr + 1][m] = tanhf(accB + b1s[m]);
  }
  __syncthreads();
  int a = lane & 15, kc = lane >> 4;
  for (int i = 0; i < 8; i++) {
    int s = s0 + i, b = s & 255;
    float p = 0.f;
    if (a < 10) {
      const float4* zp = (const float4*)(&zs[wv][i][16 * kc]);
      const float4* wp = (const float4*)(&w2s[a][16 * kc]);
      #pragma unroll
      for (int c = 0; c < 4; c++) {
        float4 zv = zp[c], w4 = wp[c];
        p += w4.x * zv.x + w4.y * zv.y + w4.z * zv.z + w4.w * zv.w;
      }
    }
    p += __shfl_xor(p, 16);
    p += __shfl_xor(p, 32);
    float val = -3.0e38f;
    if (a < 10) {
      unsigned bb1, bb2;
      tf2x32(k0, k1, 0u, (unsigned)(b * 10 + a), bb1, bb2);
      val = (p + b2s[a]) + gumbel_f(bb1 ^ bb2);
    }
    float best = 0.f; int bi = 0;
    #pragma unroll
    for (int aa = 0; aa < 10; aa++) {
      float v = __shfl(val, aa);
      if (aa == 0 || v > best) { best = v; bi = aa; }
    }
    if (lane == 0) a2_tab[(size_t)(t - 1) * 256 + b] = bi;
  }
}

// ---------------- G: gi[bt][r] = x[bt]·w_ih[r] + b_ih[r] ----------------
// No LDS. Thread = output col r (W row in 128 VGPRs, L2-resident reload/block).
// x rows are read as wave-uniform broadcast loads (scalarizable).
__global__ __launch_bounds__(384, 2) void gemm_gi(const float* __restrict__ x,
    const float* __restrict__ w_ih, const float* __restrict__ b_ih,
    float* __restrict__ gi) {
  const int tid = threadIdx.x;                 // output col 0..383
  const size_t bt0 = (size_t)blockIdx.x * 32;  // 32 rows per block
  float4 w[32];
  const float4* wg = (const float4*)(w_ih + (size_t)tid * 128);
  #pragma unroll
  for (int c = 0; c < 32; c++) w[c] = wg[c];
  const float br = b_ih[tid];
  #pragma unroll 1
  for (int i = 0; i < 32; i += 2) {
    const float4* xr0 = (const float4*)(x + (bt0 + i) * 128);
    const float4* xr1 = (const float4*)(x + (bt0 + i + 1) * 128);
    float a0x = 0.f, a0y = 0.f, a0z = 0.f, a0w = 0.f;
    float a1x = 0.f, a1y = 0.f, a1z = 0.f, a1w = 0.f;
    #pragma unroll
    for (int c = 0; c < 32; c++) {
      float4 x0 = xr0[c], x1 = xr1[c];
      a0x += w[c].x * x0.x; a0y += w[c].y * x0.y; a0z += w[c].z * x0.z; a0w += w[c].w * x0.w;
      a1x += w[c].x * x1.x; a1y += w[c].y * x1.y; a1z += w[c].z * x1.z; a1w += w[c].w * x1.w;
    }
    gi[(bt0 + i) * 384 + tid]     = ((a0x + a0y) + (a0z + a0w)) + br;
    gi[(bt0 + i + 1) * 384 + tid] = ((a1x + a1y) + (a1z + a1w)) + br;
  }
}

// ---------------- S: sequential per-batch kernel (1 block = 1 batch elem) ----------------
__global__ __launch_bounds__(512, 2) void seq_kernel(
    const float* __restrict__ gi_glob, const int* __restrict__ mask,
    const float* __restrict__ w_hh, const float* __restrict__ b_hh,
    const float* __restrict__ a1w1, const float* __restrict__ a1b1,
    const float* __restrict__ a1w2, const float* __restrict__ a1b2,
    const float* __restrict__ g1_tab, const int* __restrict__ a2_tab,
    float* __restrict__ out) {
  __shared__ __align__(16) float ring[10][128];   // ring[s] = h_s (s = t%10)
  __shared__ __align__(16) float yc[10][384];     // yc[s] = W_hh · ring[s]
  __shared__ __align__(16) float hbuf[128];       // h_{t-1}
  __shared__ __align__(16) float ghi[384];        // staged gi[b][t]
  __shared__ __align__(16) float obs6[128], obs7[128];
  __shared__ __align__(16) float z1buf[64];
  __shared__ __align__(16) float lastbuf[128];
  __shared__ __align__(16) float w1s[64 * 132];   // a1w1 rows padded to 132 floats
  __shared__ __align__(16) float w2buf[10][64];
  __shared__ float bhhs[384], b1s[64], b2s[10];
  __shared__ float g1buf[10];
  __shared__ float plogbuf[2][16];
  __shared__ int a2s_lds;
  __shared__ int redi[8];
  __shared__ int last_s;

  const int tid = threadIdx.x;
  const int wave = tid >> 6, lane = tid & 63;
  const int b = blockIdx.x;

  // ---- register-resident W_hh for waves 0-5: quad-interleaved k-split ----
  float4 wr[4][8];
  const int q = tid >> 2, qk = tid & 3;
  if (tid < 384) {
    #pragma unroll
    for (int i = 0; i < 4; i++) {
      const float* basep = w_hh + (size_t)(q + 96 * i) * 128 + 4 * qk;
      #pragma unroll
      for (int c = 0; c < 8; c++) wr[i][c] = *(const float4*)(basep + 16 * c);
    }
  }

  // ---- LDS init ----
  for (int idx = tid; idx < 1280; idx += 512) ((float*)ring)[idx] = 0.f;
  for (int idx = tid; idx < 3840; idx += 512) ((float*)yc)[idx] = 0.f;
  for (int idx = tid; idx < 8192; idx += 512) w1s[(idx >> 7) * 132 + (idx & 127)] = a1w1[idx];
  for (int idx = tid; idx < 640; idx += 512) w2buf[idx >> 6][idx & 63] = a1w2[idx];
  for (int idx = tid; idx < 384; idx += 512) bhhs[idx] = b_hh[idx];
  if (tid < 64) b1s[tid] = a1b1[tid];
  if (tid < 10) b2s[tid] = a1b2[tid];
  int mv = mask[(size_t)b * T_ + tid];
  #pragma unroll
  for (int off = 1; off < 64; off <<= 1) mv += __shfl_xor(mv, off);
  if (lane == 0) redi[wave] = mv;
  const float4* gi4 = (const float4*)gi_glob;
  float4 gir0 = make_float4(0.f,0.f,0.f,0.f), gir1 = make_float4(0.f,0.f,0.f,0.f);
  if (wave == 6) {
    size_t base1 = ((size_t)b * 512 + 1) * 96;
    gir0 = gi4[base1 + lane];
    if (lane < 32) gir1 = gi4[base1 + 64 + lane];
  }
  float g1r = 0.f; int a2r = 0;
  if (wave == 7 && lane < 10) g1r = g1_tab[(size_t)b * 10 + lane];
  if (wave == 7 && lane == 12) a2r = a2_tab[b];
  __syncthreads();
  if (tid == 0) {
    int s = 0;
    #pragma unroll
    for (int w = 0; w < 8; w++) s += redi[w];
    last_s = s - 1;
  }
  __syncthreads();
  const int last = last_s;

  // ---- t = 0: h0 = gru(x0, 0) ----
  if (tid < 128) {
    int j = tid;
    const float* g0 = gi_glob + (size_t)b * 512 * 384;
    float ir = g0[j] + bhhs[j];
    float iz = g0[128 + j] + bhhs[128 + j];
    float in_ = g0[256 + j];
    float hn = bhhs[256 + j];
    float r  = 1.0f / (1.0f + expf(-ir));
    float zz = 1.0f / (1.0f + expf(-iz));
    float n  = tanhf(in_ + r * hn);
    float hnew = (1.0f - zz) * n;
    hbuf[j] = hnew; ring[0][j] = hnew;
    if (0 == last) lastbuf[j] = hnew;
  }
  __syncthreads();

  // ---- t = 1..511 ----
  #pragma unroll 1
  for (int t = 1; t < T_; t++) {
    const int sn = (t + 9) % 10;   // slot of h_{t-1}
    if (tid < 384) {
      const float4* hb4 = (const float4*)hbuf;
      float4 a0 = make_float4(0.f,0.f,0.f,0.f), a1v = a0, a2v = a0, a3v = a0;
      #pragma unroll
      for (int c = 0; c < 8; c++) {
        float4 h4 = hb4[4 * c + qk];
        a0.x += wr[0][c].x * h4.x; a0.y += wr[0][c].y * h4.y; a0.z += wr[0][c].z * h4.z; a0.w += wr[0][c].w * h4.w;
        a1v.x += wr[1][c].x * h4.x; a1v.y += wr[1][c].y * h4.y; a1v.z += wr[1][c].z * h4.z; a1v.w += wr[1][c].w * h4.w;
        a2v.x += wr[2][c].x * h4.x; a2v.y += wr[2][c].y * h4.y; a2v.z += wr[2][c].z * h4.z; a2v.w += wr[2][c].w * h4.w;
        a3v.x += wr[3][c].x * h4.x; a3v.y += wr[3][c].y * h4.y; a3v.z += wr[3][c].z * h4.z; a3v.w += wr[3][c].w * h4.w;
      }
      float s0 = (a0.x + a0.y) + (a0.z + a0.w);
      float s1v = (a1v.x + a1v.y) + (a1v.z + a1v.w);
      float s2v = (a2v.x + a2v.y) + (a2v.z + a2v.w);
      float s3v = (a3v.x + a3v.y) + (a3v.z + a3v.w);
      s0 += __shfl_xor(s0, 1); s0 += __shfl_xor(s0, 2);
      s1v += __shfl_xor(s1v, 1); s1v += __shfl_xor(s1v, 2);
      s2v += __shfl_xor(s2v, 1); s2v += __shfl_xor(s2v, 2);
      s3v += __shfl_xor(s3v, 1); s3v += __shfl_xor(s3v, 2);
      float my = (qk == 0) ? s0 : (qk == 1) ? s1v : (qk == 2) ? s2v : s3v;
      yc[sn][q + 96 * qk] = my;
    } else if (wave == 6) {
      ((float4*)ghi)[lane] = gir0;
      if (lane < 32) ((float4*)ghi)[64 + lane] = gir1;
      if (lane < 32)
        *(float4*)(out + BH_ + ((size_t)b * 512 + (t - 1)) * 128 + 4 * lane) =
            *(const float4*)(hbuf + 4 * lane);
      if (t < 511) {
        size_t basep = ((size_t)b * 512 + t + 1) * 96;
        gir0 = gi4[basep + lane];
        if (lane < 32) gir1 = gi4[basep + 64 + lane];
      }
      float o0 = 0.f, o1 = 0.f;
      #pragma unroll
      for (int a = 0; a < 10; a++) {
        o0 += ring[(t + a) % 10][lane];
        o1 += ring[(t + a) % 10][64 + lane];
      }
      obs6[lane] = o0 / 10.0f; obs6[64 + lane] = o1 / 10.0f;
      {
        int m = lane >> 1, kc = lane & 1;
        const float* wrow = &w1s[m * 132];
        float ax = 0.f, ay = 0.f, az = 0.f, aw = 0.f;
        #pragma unroll
        for (int c = 0; c < 16; c++) {
          float4 w4 = *(const float4*)(wrow + 4 * (16 * kc + c));
          float4 o4 = ((const float4*)obs6)[16 * kc + c];
          ax += w4.x * o4.x; ay += w4.y * o4.y; az += w4.z * o4.z; aw += w4.w * o4.w;
        }
        float d = (ax + ay) + (az + aw);
        d += __shfl_xor(d, 1);
        if (kc == 0) z1buf[m] = tanhf(d + b1s[m]);
      }
      if (lane < 40) {
        int a = lane >> 2, k2 = lane & 3;
        int m0 = 8 * k2;
        float4 z4a = ((const float4*)(z1buf + m0))[0], z4b = ((const float4*)(z1buf + m0))[1];
        float4 wa = ((const float4*)(&w2buf[a][m0]))[0], wb = ((const float4*)(&w2buf[a][m0]))[1];
        float p = z4a.x*wa.x + z4a.y*wa.y + z4a.z*wa.z + z4a.w*wa.w
                + z4b.x*wb.x + z4b.y*wb.y + z4b.z*wb.z + z4b.w*wb.w;
        p += __shfl_xor(p, 1); p += __shfl_xor(p, 2);
        if (k2 == 0) plogbuf[0][a] = p;
      }
    } else { // wave 7
      if (lane < 10) g1buf[lane] = g1r;
      if (lane == 12) a2s_lds = a2r;
      if (t < 511) {
        if (lane < 10) g1r = g1_tab[((size_t)t * 256 + b) * 10 + lane];
        if (lane == 12) a2r = a2_tab[(size_t)t * 256 + b];
      }
      float o0 = 0.f, o1 = 0.f;
      #pragma unroll
      for (int a = 0; a < 10; a++) {
        o0 += ring[(t + a) % 10][lane];
        o1 += ring[(t + a) % 10][64 + lane];
      }
      obs7[lane] = o0 / 10.0f; obs7[64 + lane] = o1 / 10.0f;
      {
        int m = 32 + (lane >> 1), kc = lane & 1;
        const float* wrow = &w1s[m * 132];
        float ax = 0.f, ay = 0.f, az = 0.f, aw = 0.f;
        #pragma unroll
        for (int c = 0; c < 16; c++) {
          float4 w4 = *(const float4*)(wrow + 4 * (16 * kc + c));
          float4 o4 = ((const float4*)obs7)[16 * kc + c];
          ax += w4.x * o4.x; ay += w4.y * o4.y; az += w4.z * o4.z; aw += w4.w * o4.w;
        }
        float d = (ax + ay) + (az + aw);
        d += __shfl_xor(d, 1);
        if (kc == 0) z1buf[m] = tanhf(d + b1s[m]);
      }
      if (lane < 40) {
        int a = lane >> 2, k2 = lane & 3;
        int m0 = 32 + 8 * k2;
        float4 z4a = ((const float4*)(z1buf + m0))[0], z4b = ((const float4*)(z1buf + m0))[1];
        float4 wa = ((const float4*)(&w2buf[a][m0]))[0], wb = ((const float4*)(&w2buf[a][m0]))[1];
        float p = z4a.x*wa.x + z4a.y*wa.y + z4a.z*wa.z + z4a.w*wa.w
                + z4b.x*wb.x + z4b.y*wb.y + z4b.z*wb.z + z4b.w*wb.w;
        p += __shfl_xor(p, 1); p += __shfl_xor(p, 2);
        if (k2 == 0) plogbuf[1][a] = p;
      }
    }
    bar_lds();   // B: ycache/ghi/plog/g1buf/a2s ready (LDS-only ordering)

    float best = 0.f; int bi = 0;
    #pragma unroll
    for (int a = 0; a < 10; a++) {
      float v = (plogbuf[0][a] + plogbuf[1][a] + b2s[a]) + g1buf[a];
      if (a == 0 || v > best) { best = v; bi = a; }
    }
    const int s1 = (t + bi) % 10;
    const int s2 = (t + a2s_lds) % 10;

    if (tid < 128) {
      int j = tid;
      float gh1 = bhhs[j]       + 0.5f * (0.5f * (yc[s1][j]       + yc[s2][j]))       + 0.5f * yc[sn][j];
      float gh2 = bhhs[128 + j] + 0.5f * (0.5f * (yc[s1][128 + j] + yc[s2][128 + j])) + 0.5f * yc[sn][128 + j];
      float gh3 = bhhs[256 + j] + 0.5f * (0.5f * (yc[s1][256 + j] + yc[s2][256 + j])) + 0.5f * yc[sn][256 + j];
      float gi1 = ghi[j], gi2 = ghi[128 + j], gi3 = ghi[256 + j];
      float r  = 1.0f / (1.0f + expf(-(gi1 + gh1)));
      float zz = 1.0f / (1.0f + expf(-(gi2 + gh2)));
      float n  = tanhf(gi3 + r * gh3);
      float hw = 0.5f * ((ring[s1][j] + ring[s2][j]) * 0.5f) + 0.5f * hbuf[j];
      float hnew = (1.0f - zz) * n + zz * hw;
      hbuf[j] = hnew;
      ring[t % 10][j] = hnew;
      if (t == last) lastbuf[j] = hnew;
    }
    bar_lds();   // A for next step
  }
  if (tid < 128) {
    out[(size_t)b * H_ + tid] = lastbuf[tid];
    out[BH_ + ((size_t)b * 512 + 511) * 128 + tid] = hbuf[tid];  // h_511
  }
}

extern "C" void kernel_launch(void* const* d_in, const int* in_sizes, int n_in,
                              void* d_out, int out_size, void* d_ws, size_t ws_size,
                              hipStream_t stream) {
  (void)in_sizes; (void)n_in; (void)out_size; (void)ws_size;
  const float* x     = (const float*)d_in[0];
  const int*   mask  = (const int*)d_in[1];
  const float* w_ih  = (const float*)d_in[2];
  const float* w_hh  = (const float*)d_in[3];
  const float* b_ih  = (const float*)d_in[4];
  const float* b_hh  = (const float*)d_in[5];
  const float* a1w1  = (const float*)d_in[6];
  const float* a1b1  = (const float*)d_in[7];
  const float* a1w2  = (const float*)d_in[8];
  const float* a1b2  = (const float*)d_in[9];
  const float* a2w1  = (const float*)d_in[10];
  const float* a2b1  = (const float*)d_in[11];
  const float* a2w2  = (const float*)d_in[12];
  const float* a2b2  = (const float*)d_in[13];
  float* out = (float*)d_out;

  // workspace: gi table (201.3 MB) | g1 (5.2 MB) | keys | a2 actions
  float*    gi       = (float*)d_ws;
  float*    g1       = gi + (size_t)131072 * 384;
  unsigned* keys_tab = (unsigned*)(g1 + NG);
  int*      a2_tab   = (int*)(keys_tab + 2048);

  p0_keys<<<4, 256, 0, stream>>>(keys_tab);
  p3_gumbel<<<5110, 256, 0, stream>>>(keys_tab, g1);
  p2_a2<<<4088, 256, 0, stream>>>(x, a2w1, a2b1, a2w2, a2b2, keys_tab, a2_tab);
  gemm_gi<<<4096, 384, 0, stream>>>(x, w_ih, b_ih, gi);
  seq_kernel<<<256, 512, 0, stream>>>(gi, mask, w_hh, b_hh,
                                      a1w1, a1b1, a1w2, a1b2, g1, a2_tab, out);
}